// Round 6
// baseline (1897.753 us; speedup 1.0000x reference)
//
#include <hip/hip_runtime.h>

#define NN 100000   // nodes
#define EE 500000   // edges per relation
#define RR 3        // relations
#define LL 2        // layers
#define FF 300      // input features
#define HH 256      // hidden
#define CC 23       // classes
#define MPAD 100096 // 782 * 128
#define SCHUNK 2048
#define SNB ((NN + SCHUNK - 1) / SCHUNK)   // 49
#define CH 16384    // node-chunk for LDS hist/fill (64 KB LDS)
#define NCHUNK 7    // ceil(NN / CH)
#define HES 4       // edge-split for hist

static inline int cdiv_h(int a, int b) { return (a + b - 1) / b; }

typedef __attribute__((ext_vector_type(8))) short bf16x8;
typedef __attribute__((ext_vector_type(4))) float f32x4;
typedef __attribute__((ext_vector_type(4))) unsigned short u16x4;

__device__ inline unsigned short f2bf(float f) {
    union { float f; unsigned int u; } v; v.f = f;
    unsigned int r = v.u + 0x7fff + ((v.u >> 16) & 1);
    return (unsigned short)(r >> 16);
}
__device__ inline float bf2f(unsigned short u) {
    union { unsigned int u; float f; } v; v.u = ((unsigned int)u) << 16;
    return v.f;
}
__device__ inline void gl_lds16(const void* g, void* l) {
    __builtin_amdgcn_global_load_lds((const __attribute__((address_space(1))) unsigned int*)g,
                                     (__attribute__((address_space(3))) unsigned int*)l,
                                     16, 0, 0);
}

// ---------------------------------------------------------------------------
// CSR build — LDS-chunked (random 4B global atomics were 64B HBM line RMWs:
// hist_kernel WRITE_SIZE 93.5 MB = 1.5M edges x 64 B, 118 us).
// ---------------------------------------------------------------------------
// grid (NCHUNK, RR, 2*HES): dir = z>>2 (0: src/out, 1: dst/in), es = z&3.
__global__ __launch_bounds__(256) void hist_lds(const int* __restrict__ esrc,
                                                const int* __restrict__ edst,
                                                int* __restrict__ cnt_out,
                                                int* __restrict__ cnt_in) {
    __shared__ unsigned int h[CH];
    int chunk = blockIdx.x, r = blockIdx.y;
    int dir = blockIdx.z >> 2, es = blockIdx.z & 3;
    const int* ids = (dir ? edst : esrc) + (size_t)r * EE;
    int* cnt = (dir ? cnt_in : cnt_out) + (size_t)r * NN;
    int base = chunk * CH;
    for (int j = threadIdx.x; j < CH; j += 256) h[j] = 0;
    __syncthreads();
    const int lo4 = es * (EE / HES / 4), hi4 = lo4 + EE / HES / 4;
    const int4* ids4 = (const int4*)ids;
    for (int i = lo4 + threadIdx.x; i < hi4; i += 256) {
        int4 v = ids4[i];
        unsigned o0 = (unsigned)(v.x - base), o1 = (unsigned)(v.y - base);
        unsigned o2 = (unsigned)(v.z - base), o3 = (unsigned)(v.w - base);
        if (o0 < CH) atomicAdd(&h[o0], 1u);
        if (o1 < CH) atomicAdd(&h[o1], 1u);
        if (o2 < CH) atomicAdd(&h[o2], 1u);
        if (o3 < CH) atomicAdd(&h[o3], 1u);
    }
    __syncthreads();
    // Coalesced merge; skip zeros (most entries at HES=4 split).
    for (int j = threadIdx.x; j < CH; j += 256) {
        unsigned v = h[j];
        int idx = base + j;
        if (v && idx < NN) atomicAdd(&cnt[idx], (int)v);
    }
}

__global__ void rs_kernel(const int* __restrict__ cnt_out, const int* __restrict__ cnt_in,
                          float* __restrict__ rs_out, float* __restrict__ rs_in, int total) {
    int i = blockIdx.x * blockDim.x + threadIdx.x;
    if (i >= total) return;
    rs_out[i] = rsqrtf(fmaxf((float)cnt_out[i], 1.0f));
    rs_in[i]  = rsqrtf(fmaxf((float)cnt_in[i], 1.0f));
}

// --- 3-phase exclusive scan of in-degree counts -> CSR offsets ---
__global__ __launch_bounds__(256) void scan_a(const int* __restrict__ cnt, int* __restrict__ bsum) {
    int r = blockIdx.y, b = blockIdx.x, t = threadIdx.x;
    const int* c = cnt + (size_t)r * NN;
    int base = b * SCHUNK;
    int s = 0;
    for (int i = t; i < SCHUNK; i += 256) {
        int idx = base + i;
        if (idx < NN) s += c[idx];
    }
#pragma unroll
    for (int o = 1; o < 64; o <<= 1) s += __shfl_xor(s, o);
    __shared__ int sh[4];
    if ((t & 63) == 0) sh[t >> 6] = s;
    __syncthreads();
    if (t == 0) bsum[r * SNB + b] = sh[0] + sh[1] + sh[2] + sh[3];
}

__global__ void scan_b(int* __restrict__ bsum, int* __restrict__ offs) {
    int r = threadIdx.x;
    if (r >= RR) return;
    int* bs = bsum + r * SNB;
    int run = 0;
    for (int i = 0; i < SNB; i++) { int v = bs[i]; bs[i] = run; run += v; }
    offs[(size_t)r * (NN + 1) + NN] = run;
}

__global__ __launch_bounds__(256) void scan_c(const int* __restrict__ cnt, const int* __restrict__ bsum,
                                              int* __restrict__ offs) {
    int r = blockIdx.y, b = blockIdx.x, t = threadIdx.x;
    const int* c = cnt + (size_t)r * NN;
    int base = b * SCHUNK + t * 8;
    int v[8]; int s = 0;
#pragma unroll
    for (int j = 0; j < 8; j++) {
        int idx = base + j;
        v[j] = (idx < NN) ? c[idx] : 0;
        s += v[j];
    }
    __shared__ int sh[256];
    sh[t] = s;
    __syncthreads();
    for (int d = 1; d < 256; d <<= 1) {
        int x = (t >= d) ? sh[t - d] : 0;
        __syncthreads();
        sh[t] += x;
        __syncthreads();
    }
    int run = sh[t] - s + bsum[r * SNB + b];
    int* orow = offs + (size_t)r * (NN + 1);
#pragma unroll
    for (int j = 0; j < 8; j++) {
        int idx = base + j;
        if (idx < NN) orow[idx] = run;
        run += v[j];
    }
}

// Fill packed edge stream via LDS cursors: grid (NCHUNK, RR). Each block owns
// a 16K-node chunk: cursor atomics go to LDS; stores land in the chunk's
// CONTIGUOUS srcw region (vs 1.5M random global atomics + scattered stores).
__global__ __launch_bounds__(256) void fill_lds(const int* __restrict__ esrc,
                                                const int* __restrict__ edst,
                                                const float* __restrict__ rs_out,
                                                const int* __restrict__ offs_all,
                                                int2* __restrict__ srcw) {
    __shared__ int curL[CH];
    int chunk = blockIdx.x, r = blockIdx.y;
    int base = chunk * CH;
    const int* offs = offs_all + (size_t)r * (NN + 1);
    for (int j = threadIdx.x; j < CH; j += 256) {
        int idx = base + j;
        curL[j] = (idx < NN) ? offs[idx] : 0;
    }
    __syncthreads();
    const int4* s4p = (const int4*)(esrc + (size_t)r * EE);
    const int4* d4p = (const int4*)(edst + (size_t)r * EE);
    const float* rso = rs_out + (size_t)r * NN;
    int2* out = srcw + (size_t)r * EE;
    for (int i = threadIdx.x; i < EE / 4; i += 256) {
        int4 d4 = d4p[i];
        int4 s4 = s4p[i];
#pragma unroll
        for (int q = 0; q < 4; q++) {
            int d = (q == 0) ? d4.x : (q == 1) ? d4.y : (q == 2) ? d4.z : d4.w;
            unsigned off = (unsigned)(d - base);
            if (off < CH) {
                int s = (q == 0) ? s4.x : (q == 1) ? s4.y : (q == 2) ? s4.z : s4.w;
                int pos = atomicAdd(&curL[off], 1);
                out[pos] = make_int2(s, __float_as_int(rso[s]));
            }
        }
    }
}

// ---------------------------------------------------------------------------
// Weight prep: fp32 -> bf16, transposed to n-major [Ncols][K]
// ---------------------------------------------------------------------------
__global__ __launch_bounds__(256) void convert_x(const float* __restrict__ x, unsigned short* __restrict__ xpad) {
    int idx = blockIdx.x * blockDim.x + threadIdx.x;   // over MPAD*80
    if (idx >= MPAD * 80) return;
    int row = idx / 80, c4 = (idx - row * 80) * 4;
    ushort4 o;
    if (row < NN && c4 + 3 < FF) {   // FF % 4 == 0
        float4 v = *(const float4*)(x + (size_t)row * FF + c4);
        o.x = f2bf(v.x); o.y = f2bf(v.y); o.z = f2bf(v.z); o.w = f2bf(v.w);
    } else {
        o.x = 0; o.y = 0; o.z = 0; o.w = 0;
    }
    *(ushort4*)(xpad + (size_t)row * 320 + c4) = o;
}

__global__ void wprep_feat(const float* __restrict__ W, unsigned short* __restrict__ Bt) {
    int n = blockIdx.x;
    int k = threadIdx.x;
    float v = (k < FF) ? W[(size_t)k * HH + n] : 0.f;
    Bt[(size_t)n * 320 + k] = f2bf(v);
}

__global__ void wprep_layer(const float* __restrict__ skipW, const float* __restrict__ gcnW,
                            unsigned short* __restrict__ Bt) {
    int idx = blockIdx.x * blockDim.x + threadIdx.x;
    int n = idx >> 10, k = idx & 1023;
    int seg = k >> 8, k2 = k & 255;
    float v = (seg == 0) ? skipW[(size_t)k2 * HH + n]
                         : gcnW[(size_t)(seg - 1) * HH * HH + (size_t)k2 * HH + n] * (1.0f / 3.0f);
    Bt[(size_t)n * 1024 + k] = f2bf(v);
}

__global__ void bias_layer(const float* __restrict__ skip_b, const float* __restrict__ gcn_b,
                           float* __restrict__ bias) {
    int t = threadIdx.x;
    bias[t] = skip_b[t] + (gcn_b[t] + gcn_b[HH + t] + gcn_b[2 * HH + t]) * (1.0f / 3.0f);
}

__global__ void wprep_c1(const float* __restrict__ W, unsigned short* __restrict__ Bt) {
    int idx = blockIdx.x * blockDim.x + threadIdx.x;
    int n = idx >> 8, k = idx & 255;
    Bt[(size_t)n * HH + k] = f2bf(W[(size_t)k * HH + n]);
}

__global__ void wprep_c2(const float* __restrict__ W, unsigned short* __restrict__ Bt) {
    int n = blockIdx.x;   // 0..255 (rows >= CC zero-padded for the 256-wide N tile)
    int k = threadIdx.x;
    float v = (n < CC) ? W[(size_t)k * CC + n] : 0.f;
    Bt[(size_t)n * HH + k] = f2bf(v);
}

// ---------------------------------------------------------------------------
// Aggregation (bf16), full-width (R2-verified): grid (NN/4, RR).
// One wave per dst node; lane covers 4 cols (ushort4, 8 B/lane).
// ---------------------------------------------------------------------------
__global__ __launch_bounds__(256) void agg_bf16(unsigned short* __restrict__ hcat,
                                                const int* __restrict__ offs_all,
                                                const int2* __restrict__ srcw_all,
                                                const float* __restrict__ rs_in_all) {
    int r = blockIdx.y;
    const int* offs = offs_all + (size_t)r * (NN + 1);
    const int2* srcw = srcw_all + (size_t)r * EE;
    const float* rs_i = rs_in_all + (size_t)r * NN;
    int wave = threadIdx.x >> 6;
    int lane = threadIdx.x & 63;
    int node = blockIdx.x * 4 + wave;
    if (node >= NN) return;
    int s0 = __builtin_amdgcn_readfirstlane(offs[node]);
    int s1 = __builtin_amdgcn_readfirstlane(offs[node + 1]);
    int cnt = s1 - s0;
    const int2* ew = srcw + s0;
    const unsigned short* hb = hcat + lane * 4;
    float a0 = 0.f, a1 = 0.f, a2 = 0.f, a3 = 0.f;
    int k = 0;
    for (; k + 8 <= cnt; k += 8) {
        int2 e[8];
#pragma unroll
        for (int q = 0; q < 8; q++) e[q] = ew[k + q];
        ushort4 hv[8];
#pragma unroll
        for (int q = 0; q < 8; q++) hv[q] = *(const ushort4*)(hb + (size_t)e[q].x * 1024);
#pragma unroll
        for (int q = 0; q < 8; q++) {
            float u = __int_as_float(e[q].y);
            a0 += u * bf2f(hv[q].x); a1 += u * bf2f(hv[q].y);
            a2 += u * bf2f(hv[q].z); a3 += u * bf2f(hv[q].w);
        }
    }
    if (k + 4 <= cnt) {
        int2 e[4];
#pragma unroll
        for (int q = 0; q < 4; q++) e[q] = ew[k + q];
        ushort4 hv[4];
#pragma unroll
        for (int q = 0; q < 4; q++) hv[q] = *(const ushort4*)(hb + (size_t)e[q].x * 1024);
#pragma unroll
        for (int q = 0; q < 4; q++) {
            float u = __int_as_float(e[q].y);
            a0 += u * bf2f(hv[q].x); a1 += u * bf2f(hv[q].y);
            a2 += u * bf2f(hv[q].z); a3 += u * bf2f(hv[q].w);
        }
        k += 4;
    }
    int rem = cnt - k;  // 0..3
    if (rem > 0) {
        int2 e[3];
#pragma unroll
        for (int q = 0; q < 3; q++) {
            int kk = k + q; if (kk > cnt - 1) kk = cnt - 1;
            e[q] = ew[kk];
        }
        ushort4 hv[3];
#pragma unroll
        for (int q = 0; q < 3; q++) hv[q] = *(const ushort4*)(hb + (size_t)e[q].x * 1024);
        float u0 = __int_as_float(e[0].y);
        float u1 = rem > 1 ? __int_as_float(e[1].y) : 0.f;
        float u2 = rem > 2 ? __int_as_float(e[2].y) : 0.f;
        a0 += u0 * bf2f(hv[0].x) + u1 * bf2f(hv[1].x) + u2 * bf2f(hv[2].x);
        a1 += u0 * bf2f(hv[0].y) + u1 * bf2f(hv[1].y) + u2 * bf2f(hv[2].y);
        a2 += u0 * bf2f(hv[0].z) + u1 * bf2f(hv[1].z) + u2 * bf2f(hv[2].z);
        a3 += u0 * bf2f(hv[0].w) + u1 * bf2f(hv[1].w) + u2 * bf2f(hv[2].w);
    }
    float wi = rs_i[node];
    u16x4 o;
    o.x = f2bf(a0 * wi); o.y = f2bf(a1 * wi);
    o.z = f2bf(a2 * wi); o.w = f2bf(a3 * wi);
    __builtin_nontemporal_store(o, (u16x4*)(hcat + (size_t)node * 1024 + 256 * (r + 1) + lane * 4));
}

// ---------------------------------------------------------------------------
// bf16 MFMA GEMM — R2-verified 2-sync K-loop + LDS-staged C epilogue
// (best measured: 117.7 us @ K=1024, FETCH 104 MB, WRITE 55 MB).
// BM=128, BN=256, BK=64, 512 thr/8 waves; LDS 66 KB => 2 blocks/CU.
// ---------------------------------------------------------------------------
__global__ __launch_bounds__(512, 4) void mfma_gemm(const unsigned short* __restrict__ A, int ldA,
                                                    const unsigned short* __restrict__ Bt,
                                                    const float* __restrict__ bias,
                                                    void* __restrict__ Cv, int ldC,
                                                    int Nstore, int K, int c_bf16,
                                                    float* __restrict__ stats) {
    __shared__ unsigned short lds[33792];   // 66 KB
    int tid = threadIdx.x;
    int w = tid >> 6, lane = tid & 63;
    int quad = lane >> 4, lr = lane & 15;
    int bm = blockIdx.y * 128;
    int wm = w >> 2, wn = w & 3;        // 2x4 wave grid, 64x64 C-tile per wave
    int lrow = lane >> 2;
    int lslot = lane & 3;

    f32x4 acc[4][4];
#pragma unroll
    for (int i = 0; i < 4; i++)
#pragma unroll
        for (int j = 0; j < 4; j++) acc[i][j] = (f32x4){0.f, 0.f, 0.f, 0.f};

    for (int k0 = 0; k0 < K; k0 += 64) {
        int rA = w * 16 + lrow;
        int cgA = lslot ^ ((rA >> 1) & 3);
#pragma unroll
        for (int h = 0; h < 2; h++) {
            gl_lds16(A + (size_t)(bm + rA) * ldA + k0 + h * 32 + cgA * 8,
                     &lds[h * 4096 + w * 512]);
#pragma unroll
            for (int c = 0; c < 2; c++) {
                int cc = w * 2 + c;
                int rB = cc * 16 + lrow;
                int cgB = lslot ^ ((rB >> 1) & 3);
                gl_lds16(Bt + (size_t)rB * K + k0 + h * 32 + cgB * 8,
                         &lds[8192 + h * 8192 + cc * 512]);
            }
        }
        __syncthreads();
#pragma unroll
        for (int h = 0; h < 2; h++) {
            bf16x8 af[4], bfr[4];
#pragma unroll
            for (int i = 0; i < 4; i++) {
                int r = wm * 64 + i * 16 + lr;
                int s = quad ^ ((r >> 1) & 3);
                af[i] = *(const bf16x8*)&lds[h * 4096 + r * 32 + s * 8];
            }
#pragma unroll
            for (int j = 0; j < 4; j++) {
                int n = wn * 64 + j * 16 + lr;
                int s = quad ^ ((n >> 1) & 3);
                bfr[j] = *(const bf16x8*)&lds[8192 + h * 8192 + n * 32 + s * 8];
            }
#pragma unroll
            for (int i = 0; i < 4; i++)
#pragma unroll
                for (int j = 0; j < 4; j++)
                    acc[i][j] = __builtin_amdgcn_mfma_f32_16x16x32_bf16(af[i], bfr[j], acc[i][j], 0, 0, 0);
        }
        __syncthreads();
    }

    if (c_bf16) {
        unsigned short* ldsC = lds;    // [128][264] padded stride
#pragma unroll
        for (int j = 0; j < 4; j++) {
            int col = wn * 64 + j * 16 + lr;
            float bv = bias ? bias[col] : 0.f;
            float ssum = 0.f, ssq = 0.f;
#pragma unroll
            for (int i = 0; i < 4; i++) {
#pragma unroll
                for (int v = 0; v < 4; v++) {
                    int row = wm * 64 + i * 16 + quad * 4 + v;
                    float val = acc[i][j][v] + bv;
                    ldsC[row * 264 + col] = f2bf(val);
                    if (bm + row < NN) { ssum += val; ssq += val * val; }
                }
            }
            if (stats) {
                ssum += __shfl_xor(ssum, 16); ssum += __shfl_xor(ssum, 32);
                ssq  += __shfl_xor(ssq, 16);  ssq  += __shfl_xor(ssq, 32);
                if (quad == 0) {
                    atomicAdd(&stats[col], ssum);
                    atomicAdd(&stats[HH + col], ssq);
                }
            }
        }
        __syncthreads();
        int row = tid >> 2, seg = tid & 3;
        if (bm + row < NN) {
            const unsigned short* srcp = ldsC + row * 264 + seg * 64;
            unsigned short* dstp = (unsigned short*)Cv + (size_t)(bm + row) * ldC + seg * 64;
#pragma unroll
            for (int q = 0; q < 8; q++)
                *(uint4*)(dstp + q * 8) = *(const uint4*)(srcp + q * 8);
        }
    } else {
        float* Cf = (float*)Cv;
#pragma unroll
        for (int j = 0; j < 4; j++) {
            int col = wn * 64 + j * 16 + lr;
            if (col >= Nstore) continue;
            float bv = bias ? bias[col] : 0.f;
#pragma unroll
            for (int i = 0; i < 4; i++) {
#pragma unroll
                for (int v = 0; v < 4; v++) {
                    int row = bm + wm * 64 + i * 16 + quad * 4 + v;
                    if (row < NN) Cf[(size_t)row * ldC + col] = acc[i][j][v] + bv;
                }
            }
        }
    }
}

// ---------------------------------------------------------------------------
// BN: coef precompute + vectorized apply (bf16 in, bf16 out at ld=1024)
// ---------------------------------------------------------------------------
__global__ void bn_coef(const float* __restrict__ stats, const float* __restrict__ g,
                        const float* __restrict__ b, float* __restrict__ coef, float invM) {
    int c = threadIdx.x;
    float mean = stats[c] * invM;
    float var = stats[HH + c] * invM - mean * mean;
    float inv = rsqrtf(var + 1e-5f);
    float sc = g[c] * inv;
    coef[c] = sc;
    coef[HH + c] = b[c] - mean * sc;
}

// act: 1 = relu, 2 = leaky relu (0.01)
__global__ __launch_bounds__(256) void bn_apply_v(const unsigned short* __restrict__ Z,
                                                  const float* __restrict__ coef,
                                                  unsigned short* __restrict__ out, int act) {
    int idx = blockIdx.x * blockDim.x + threadIdx.x;
    if (idx >= NN * 32) return;
    int row = idx >> 5, cg = (idx & 31) * 8;
    union { uint4 u; unsigned short s[8]; } zin, zo;
    zin.u = *(const uint4*)(Z + (size_t)row * HH + cg);
    f32x4 sc0 = *(const f32x4*)(coef + cg);
    f32x4 sc1 = *(const f32x4*)(coef + cg + 4);
    f32x4 sh0 = *(const f32x4*)(coef + HH + cg);
    f32x4 sh1 = *(const f32x4*)(coef + HH + cg + 4);
#pragma unroll
    for (int j = 0; j < 8; j++) {
        float sc = (j < 4) ? sc0[j] : sc1[j - 4];
        float sh = (j < 4) ? sh0[j] : sh1[j - 4];
        float v = bf2f(zin.s[j]) * sc + sh;
        if (act == 1) v = fmaxf(v, 0.f);
        else v = (v < 0.f) ? 0.01f * v : v;
        zo.s[j] = f2bf(v);
    }
    *(uint4*)(out + (size_t)row * 1024 + cg) = zo.u;
}

// ---------------------------------------------------------------------------
extern "C" void kernel_launch(void* const* d_in, const int* in_sizes, int n_in,
                              void* d_out, int out_size, void* d_ws, size_t ws_size,
                              hipStream_t stream) {
    const float* x        = (const float*)d_in[0];
    const int*   esrc     = (const int*)d_in[1];
    const int*   edst     = (const int*)d_in[2];
    const float* W_feat   = (const float*)d_in[3];
    const float* b_feat   = (const float*)d_in[4];
    const float* g_feat   = (const float*)d_in[5];
    const float* beta_feat= (const float*)d_in[6];
    const float* gcn_W    = (const float*)d_in[7];
    const float* gcn_b    = (const float*)d_in[8];
    const float* skip_W   = (const float*)d_in[9];
    const float* skip_b   = (const float*)d_in[10];
    const float* bn_g     = (const float*)d_in[11];
    const float* bn_b     = (const float*)d_in[12];
    const float* W_c1     = (const float*)d_in[13];
    const float* b_c1     = (const float*)d_in[14];
    const float* g_c      = (const float*)d_in[15];
    const float* beta_c   = (const float*)d_in[16];
    const float* W_c2     = (const float*)d_in[17];
    const float* b_c2     = (const float*)d_in[18];
    float* out = (float*)d_out;
    (void)in_sizes; (void)n_in; (void)out_size; (void)ws_size;

    char* w = (char*)d_ws;
    size_t off = 0;
    auto alloc = [&](size_t bytes) { void* p = w + off; off += (bytes + 255) & ~(size_t)255; return p; };
    unsigned short* hcat = (unsigned short*)alloc((size_t)MPAD * 1024 * 2);
    unsigned short* xpad = hcat;  // [MPAD][320] bf16, dead after feat GEMM
    unsigned short* c_acc = (unsigned short*)alloc((size_t)NN * HH * 2);  // bf16 pre-BN C
    float* f_stats = (float*)alloc(4 * 2 * HH * 4);   // 4 slices of [2][HH]
    float* f_coef  = (float*)alloc(2 * HH * 4);
    float* f_rs_out = (float*)alloc((size_t)RR * NN * 4);
    float* f_rs_in  = (float*)alloc((size_t)RR * NN * 4);
    int* i_cnt_out = (int*)alloc((size_t)RR * NN * 4);
    int* i_cnt_in  = (int*)alloc((size_t)RR * NN * 4);
    int* i_off     = (int*)alloc((size_t)RR * (NN + 1) * 4);
    int2* i_srcw   = (int2*)alloc((size_t)RR * EE * 8);
    int* i_bsum    = (int*)alloc((size_t)RR * SNB * 4);
    unsigned short* Bt_feat = (unsigned short*)alloc(256 * 320 * 2);
    unsigned short* Bt_l0   = (unsigned short*)alloc(256 * 1024 * 2);
    unsigned short* Bt_l1   = (unsigned short*)alloc(256 * 1024 * 2);
    unsigned short* Bt_c1   = (unsigned short*)alloc(256 * 256 * 2);
    unsigned short* Bt_c2   = (unsigned short*)alloc(256 * 256 * 2);  // padded to 256 rows
    float* bias_l0 = (float*)alloc(HH * 4);
    float* bias_l1 = (float*)alloc(HH * 4);

    const float invM = 1.0f / (float)NN;

    // --- CSR + degrees (LDS-chunked) ---
    (void)hipMemsetAsync(i_cnt_out, 0, (size_t)RR * NN * 4, stream);
    (void)hipMemsetAsync(i_cnt_in, 0, (size_t)RR * NN * 4, stream);
    (void)hipMemsetAsync(f_stats, 0, 4 * 2 * HH * 4, stream);
    hist_lds<<<dim3(NCHUNK, RR, 2 * HES), 256, 0, stream>>>(esrc, edst, i_cnt_out, i_cnt_in);
    rs_kernel<<<cdiv_h(RR * NN, 256), 256, 0, stream>>>(i_cnt_out, i_cnt_in, f_rs_out, f_rs_in, RR * NN);
    scan_a<<<dim3(SNB, RR), 256, 0, stream>>>(i_cnt_in, i_bsum);
    scan_b<<<1, 64, 0, stream>>>(i_bsum, i_off);
    scan_c<<<dim3(SNB, RR), 256, 0, stream>>>(i_cnt_in, i_bsum, i_off);
    fill_lds<<<dim3(NCHUNK, RR), 256, 0, stream>>>(esrc, edst, f_rs_out, i_off, i_srcw);

    // --- weight prep (bf16, transposed) ---
    convert_x<<<cdiv_h(MPAD * 80, 256), 256, 0, stream>>>(x, xpad);
    wprep_feat<<<256, 320, 0, stream>>>(W_feat, Bt_feat);
    wprep_layer<<<1024, 256, 0, stream>>>(skip_W, gcn_W, Bt_l0);
    wprep_layer<<<1024, 256, 0, stream>>>(skip_W + (size_t)HH * HH, gcn_W + (size_t)RR * HH * HH, Bt_l1);
    bias_layer<<<1, 256, 0, stream>>>(skip_b, gcn_b, bias_l0);
    bias_layer<<<1, 256, 0, stream>>>(skip_b + HH, gcn_b + (size_t)RR * HH, bias_l1);
    wprep_c1<<<256, 256, 0, stream>>>(W_c1, Bt_c1);
    wprep_c2<<<256, 256, 0, stream>>>(W_c2, Bt_c2);

    dim3 grid_G(1, MPAD / 128);   // BN=256 covers the full N in one tile column
    dim3 grid_A(cdiv_h(NN, 4), RR);
    const int nblk_a = cdiv_h(NN * 32, 256);
    float* st0 = f_stats;
    float* st1 = f_stats + 2 * HH;
    float* st2 = f_stats + 4 * HH;
    float* st3 = f_stats + 6 * HH;

    // --- feat_reduce: h = relu(BN(x @ W_feat + b_feat)) -> hcat[:,0:256] bf16 ---
    mfma_gemm<<<grid_G, 512, 0, stream>>>(xpad, 320, Bt_feat, b_feat, c_acc, HH, HH, 320, 1, st0);
    bn_coef<<<1, 256, 0, stream>>>(st0, g_feat, beta_feat, f_coef, invM);
    bn_apply_v<<<nblk_a, 256, 0, stream>>>(c_acc, f_coef, hcat, 1);

    // --- GCN layers: one K=1024 GEMM per layer ---
    for (int l = 0; l < LL; l++) {
        agg_bf16<<<grid_A, 256, 0, stream>>>(hcat, i_off, i_srcw, f_rs_in);
        float* st = l ? st2 : st1;
        mfma_gemm<<<grid_G, 512, 0, stream>>>(hcat, 1024, l ? Bt_l1 : Bt_l0,
                                              l ? bias_l1 : bias_l0, c_acc, HH, HH, 1024, 1, st);
        bn_coef<<<1, 256, 0, stream>>>(st, bn_g + (size_t)l * HH, bn_b + (size_t)l * HH, f_coef, invM);
        bn_apply_v<<<nblk_a, 256, 0, stream>>>(c_acc, f_coef, hcat, 2);
    }

    // --- head ---
    mfma_gemm<<<grid_G, 512, 0, stream>>>(hcat, 1024, Bt_c1, b_c1, c_acc, HH, HH, 256, 1, st3);
    bn_coef<<<1, 256, 0, stream>>>(st3, g_c, beta_c, f_coef, invM);
    bn_apply_v<<<nblk_a, 256, 0, stream>>>(c_acc, f_coef, hcat + 256, 1);
    mfma_gemm<<<grid_G, 512, 0, stream>>>(hcat + 256, 1024, Bt_c2, b_c2, out, CC, CC, 256, 0, nullptr);
}

// Round 7
// 1171.215 us; speedup vs baseline: 1.6203x; 1.6203x over previous
//
#include <hip/hip_runtime.h>

#define NN 100000   // nodes
#define EE 500000   // edges per relation
#define RR 3        // relations
#define LL 2        // layers
#define FF 300      // input features
#define HH 256      // hidden
#define CC 23       // classes
#define MPAD 100096 // 782 * 128
#define SCHUNK 2048
#define SNB ((NN + SCHUNK - 1) / SCHUNK)   // 49
#define CH 16384    // node-chunk for LDS hist/fill (64 KB LDS)
#define NCHUNK 7    // ceil(NN / CH)
#define ES 25       // edge slices (EE/ES = 20000 edges, 5000 int4 per slice)
#define EES4 (EE / ES / 4)   // 5000

static inline int cdiv_h(int a, int b) { return (a + b - 1) / b; }

typedef __attribute__((ext_vector_type(8))) short bf16x8;
typedef __attribute__((ext_vector_type(4))) float f32x4;
typedef __attribute__((ext_vector_type(4))) unsigned short u16x4;

__device__ inline unsigned short f2bf(float f) {
    union { float f; unsigned int u; } v; v.f = f;
    unsigned int r = v.u + 0x7fff + ((v.u >> 16) & 1);
    return (unsigned short)(r >> 16);
}
__device__ inline float bf2f(unsigned short u) {
    union { unsigned int u; float f; } v; v.u = ((unsigned int)u) << 16;
    return v.f;
}
__device__ inline void gl_lds16(const void* g, void* l) {
    __builtin_amdgcn_global_load_lds((const __attribute__((address_space(1))) unsigned int*)g,
                                     (__attribute__((address_space(3))) unsigned int*)l,
                                     16, 0, 0);
}

// ---------------------------------------------------------------------------
// CSR build — LDS-chunked with edge-slice parallelism (fill_lds at grid=21
// was 877 us / 0.87% occupancy; now 525 blocks with per-slice cursor bases).
// ---------------------------------------------------------------------------
// Out-degrees: grid (NCHUNK, RR, 4 edge-splits); LDS hist + atomic merge.
__global__ __launch_bounds__(256) void hist_out(const int* __restrict__ esrc,
                                                int* __restrict__ cnt_out) {
    __shared__ unsigned int h[CH];
    int chunk = blockIdx.x, r = blockIdx.y, es = blockIdx.z;
    const int* ids = esrc + (size_t)r * EE;
    int* cnt = cnt_out + (size_t)r * NN;
    int base = chunk * CH;
    for (int j = threadIdx.x; j < CH; j += 256) h[j] = 0;
    __syncthreads();
    const int lo4 = es * (EE / 4 / 4), hi4 = lo4 + EE / 4 / 4;
    const int4* ids4 = (const int4*)ids;
    for (int i = lo4 + threadIdx.x; i < hi4; i += 256) {
        int4 v = ids4[i];
        unsigned o0 = (unsigned)(v.x - base), o1 = (unsigned)(v.y - base);
        unsigned o2 = (unsigned)(v.z - base), o3 = (unsigned)(v.w - base);
        if (o0 < CH) atomicAdd(&h[o0], 1u);
        if (o1 < CH) atomicAdd(&h[o1], 1u);
        if (o2 < CH) atomicAdd(&h[o2], 1u);
        if (o3 < CH) atomicAdd(&h[o3], 1u);
    }
    __syncthreads();
    for (int j = threadIdx.x; j < CH; j += 256) {
        unsigned v = h[j];
        int idx = base + j;
        if (v && idx < NN) atomicAdd(&cnt[idx], (int)v);
    }
}

// Per-slice in-degree counts: grid (NCHUNK, RR, ES). Single writer per
// (s,r,n) -> plain stores, no global atomics. cnt_s[((s*RR)+r)*NN + n].
__global__ __launch_bounds__(256) void hist_slice(const int* __restrict__ edst,
                                                  int* __restrict__ cnt_s) {
    __shared__ unsigned int h[CH];
    int chunk = blockIdx.x, r = blockIdx.y, s = blockIdx.z;
    int base = chunk * CH;
    for (int j = threadIdx.x; j < CH; j += 256) h[j] = 0;
    __syncthreads();
    const int4* d4p = (const int4*)(edst + (size_t)r * EE);
    const int lo = s * EES4, hi = lo + EES4;
    for (int i = lo + threadIdx.x; i < hi; i += 256) {
        int4 v = d4p[i];
        unsigned o0 = (unsigned)(v.x - base), o1 = (unsigned)(v.y - base);
        unsigned o2 = (unsigned)(v.z - base), o3 = (unsigned)(v.w - base);
        if (o0 < CH) atomicAdd(&h[o0], 1u);
        if (o1 < CH) atomicAdd(&h[o1], 1u);
        if (o2 < CH) atomicAdd(&h[o2], 1u);
        if (o3 < CH) atomicAdd(&h[o3], 1u);
    }
    __syncthreads();
    int* dst = cnt_s + ((size_t)s * RR + r) * NN;
    for (int j = threadIdx.x; j < CH; j += 256) {
        int idx = base + j;
        if (idx < NN) dst[idx] = (int)h[j];
    }
}

// cnt_in[r][n] = sum_s cnt_s[s][r][n]
__global__ void sum_slices(const int* __restrict__ cnt_s, int* __restrict__ cnt_in) {
    int i = blockIdx.x * blockDim.x + threadIdx.x;
    if (i >= RR * NN) return;
    int r = i / NN, n = i - r * NN;
    int sum = 0;
#pragma unroll 5
    for (int s = 0; s < ES; s++) sum += cnt_s[((size_t)s * RR + r) * NN + n];
    cnt_in[i] = sum;
}

__global__ void rs_kernel(const int* __restrict__ cnt_out, const int* __restrict__ cnt_in,
                          float* __restrict__ rs_out, float* __restrict__ rs_in, int total) {
    int i = blockIdx.x * blockDim.x + threadIdx.x;
    if (i >= total) return;
    rs_out[i] = rsqrtf(fmaxf((float)cnt_out[i], 1.0f));
    rs_in[i]  = rsqrtf(fmaxf((float)cnt_in[i], 1.0f));
}

// --- 3-phase exclusive scan of in-degree counts -> CSR offsets ---
__global__ __launch_bounds__(256) void scan_a(const int* __restrict__ cnt, int* __restrict__ bsum) {
    int r = blockIdx.y, b = blockIdx.x, t = threadIdx.x;
    const int* c = cnt + (size_t)r * NN;
    int base = b * SCHUNK;
    int s = 0;
    for (int i = t; i < SCHUNK; i += 256) {
        int idx = base + i;
        if (idx < NN) s += c[idx];
    }
#pragma unroll
    for (int o = 1; o < 64; o <<= 1) s += __shfl_xor(s, o);
    __shared__ int sh[4];
    if ((t & 63) == 0) sh[t >> 6] = s;
    __syncthreads();
    if (t == 0) bsum[r * SNB + b] = sh[0] + sh[1] + sh[2] + sh[3];
}

__global__ void scan_b(int* __restrict__ bsum, int* __restrict__ offs) {
    int r = threadIdx.x;
    if (r >= RR) return;
    int* bs = bsum + r * SNB;
    int run = 0;
    for (int i = 0; i < SNB; i++) { int v = bs[i]; bs[i] = run; run += v; }
    offs[(size_t)r * (NN + 1) + NN] = run;
}

__global__ __launch_bounds__(256) void scan_c(const int* __restrict__ cnt, const int* __restrict__ bsum,
                                              int* __restrict__ offs) {
    int r = blockIdx.y, b = blockIdx.x, t = threadIdx.x;
    const int* c = cnt + (size_t)r * NN;
    int base = b * SCHUNK + t * 8;
    int v[8]; int s = 0;
#pragma unroll
    for (int j = 0; j < 8; j++) {
        int idx = base + j;
        v[j] = (idx < NN) ? c[idx] : 0;
        s += v[j];
    }
    __shared__ int sh[256];
    sh[t] = s;
    __syncthreads();
    for (int d = 1; d < 256; d <<= 1) {
        int x = (t >= d) ? sh[t - d] : 0;
        __syncthreads();
        sh[t] += x;
        __syncthreads();
    }
    int run = sh[t] - s + bsum[r * SNB + b];
    int* orow = offs + (size_t)r * (NN + 1);
#pragma unroll
    for (int j = 0; j < 8; j++) {
        int idx = base + j;
        if (idx < NN) orow[idx] = run;
        run += v[j];
    }
}

// In-place exclusive scan of cnt_s over s per (r,n): cnt_s becomes per-slice
// cursor base. Must run AFTER sum_slices (which reads raw counts) and scan.
__global__ void prefix_slices(const int* __restrict__ offs_all, int* __restrict__ cnt_s) {
    int i = blockIdx.x * blockDim.x + threadIdx.x;
    if (i >= RR * NN) return;
    int r = i / NN, n = i - r * NN;
    int base = offs_all[(size_t)r * (NN + 1) + n];
    for (int s = 0; s < ES; s++) {
        size_t idx = ((size_t)s * RR + r) * NN + n;
        int c = cnt_s[idx];
        cnt_s[idx] = base;
        base += c;
    }
}

// Fill packed edge stream: grid (NCHUNK, RR, ES) = 525 blocks. LDS cursors
// seeded from per-slice bases; each block touches only its 20K-edge slice.
__global__ __launch_bounds__(256) void fill_sliced(const int* __restrict__ esrc,
                                                   const int* __restrict__ edst,
                                                   const float* __restrict__ rs_out,
                                                   const int* __restrict__ posbase,
                                                   int2* __restrict__ srcw) {
    __shared__ int curL[CH];
    int chunk = blockIdx.x, r = blockIdx.y, s = blockIdx.z;
    int base = chunk * CH;
    const int* pb = posbase + ((size_t)s * RR + r) * NN;
    for (int j = threadIdx.x; j < CH; j += 256) {
        int idx = base + j;
        curL[j] = (idx < NN) ? pb[idx] : 0;
    }
    __syncthreads();
    const int4* s4p = (const int4*)(esrc + (size_t)r * EE);
    const int4* d4p = (const int4*)(edst + (size_t)r * EE);
    const float* rso = rs_out + (size_t)r * NN;
    int2* out = srcw + (size_t)r * EE;
    const int lo = s * EES4, hi = lo + EES4;
    for (int i = lo + threadIdx.x; i < hi; i += 256) {
        int4 d4 = d4p[i];
        int4 s4 = s4p[i];
#pragma unroll
        for (int q = 0; q < 4; q++) {
            int d = (q == 0) ? d4.x : (q == 1) ? d4.y : (q == 2) ? d4.z : d4.w;
            unsigned o = (unsigned)(d - base);
            if (o < CH) {
                int sv = (q == 0) ? s4.x : (q == 1) ? s4.y : (q == 2) ? s4.z : s4.w;
                int pos = atomicAdd(&curL[o], 1);
                out[pos] = make_int2(sv, __float_as_int(rso[sv]));
            }
        }
    }
}

// ---------------------------------------------------------------------------
// Weight prep: fp32 -> bf16, transposed to n-major [Ncols][K]
// ---------------------------------------------------------------------------
__global__ __launch_bounds__(256) void convert_x(const float* __restrict__ x, unsigned short* __restrict__ xpad) {
    int idx = blockIdx.x * blockDim.x + threadIdx.x;   // over MPAD*80
    if (idx >= MPAD * 80) return;
    int row = idx / 80, c4 = (idx - row * 80) * 4;
    ushort4 o;
    if (row < NN && c4 + 3 < FF) {   // FF % 4 == 0
        float4 v = *(const float4*)(x + (size_t)row * FF + c4);
        o.x = f2bf(v.x); o.y = f2bf(v.y); o.z = f2bf(v.z); o.w = f2bf(v.w);
    } else {
        o.x = 0; o.y = 0; o.z = 0; o.w = 0;
    }
    *(ushort4*)(xpad + (size_t)row * 320 + c4) = o;
}

__global__ void wprep_feat(const float* __restrict__ W, unsigned short* __restrict__ Bt) {
    int n = blockIdx.x;
    int k = threadIdx.x;
    float v = (k < FF) ? W[(size_t)k * HH + n] : 0.f;
    Bt[(size_t)n * 320 + k] = f2bf(v);
}

__global__ void wprep_layer(const float* __restrict__ skipW, const float* __restrict__ gcnW,
                            unsigned short* __restrict__ Bt) {
    int idx = blockIdx.x * blockDim.x + threadIdx.x;
    int n = idx >> 10, k = idx & 1023;
    int seg = k >> 8, k2 = k & 255;
    float v = (seg == 0) ? skipW[(size_t)k2 * HH + n]
                         : gcnW[(size_t)(seg - 1) * HH * HH + (size_t)k2 * HH + n] * (1.0f / 3.0f);
    Bt[(size_t)n * 1024 + k] = f2bf(v);
}

__global__ void bias_layer(const float* __restrict__ skip_b, const float* __restrict__ gcn_b,
                           float* __restrict__ bias) {
    int t = threadIdx.x;
    bias[t] = skip_b[t] + (gcn_b[t] + gcn_b[HH + t] + gcn_b[2 * HH + t]) * (1.0f / 3.0f);
}

__global__ void wprep_c1(const float* __restrict__ W, unsigned short* __restrict__ Bt) {
    int idx = blockIdx.x * blockDim.x + threadIdx.x;
    int n = idx >> 8, k = idx & 255;
    Bt[(size_t)n * HH + k] = f2bf(W[(size_t)k * HH + n]);
}

__global__ void wprep_c2(const float* __restrict__ W, unsigned short* __restrict__ Bt) {
    int n = blockIdx.x;   // 0..255 (rows >= CC zero-padded for the 256-wide N tile)
    int k = threadIdx.x;
    float v = (n < CC) ? W[(size_t)k * CC + n] : 0.f;
    Bt[(size_t)n * HH + k] = f2bf(v);
}

// ---------------------------------------------------------------------------
// Aggregation (bf16), full-width (R2-verified): grid (NN/4, RR).
// ---------------------------------------------------------------------------
__global__ __launch_bounds__(256) void agg_bf16(unsigned short* __restrict__ hcat,
                                                const int* __restrict__ offs_all,
                                                const int2* __restrict__ srcw_all,
                                                const float* __restrict__ rs_in_all) {
    int r = blockIdx.y;
    const int* offs = offs_all + (size_t)r * (NN + 1);
    const int2* srcw = srcw_all + (size_t)r * EE;
    const float* rs_i = rs_in_all + (size_t)r * NN;
    int wave = threadIdx.x >> 6;
    int lane = threadIdx.x & 63;
    int node = blockIdx.x * 4 + wave;
    if (node >= NN) return;
    int s0 = __builtin_amdgcn_readfirstlane(offs[node]);
    int s1 = __builtin_amdgcn_readfirstlane(offs[node + 1]);
    int cnt = s1 - s0;
    const int2* ew = srcw + s0;
    const unsigned short* hb = hcat + lane * 4;
    float a0 = 0.f, a1 = 0.f, a2 = 0.f, a3 = 0.f;
    int k = 0;
    for (; k + 8 <= cnt; k += 8) {
        int2 e[8];
#pragma unroll
        for (int q = 0; q < 8; q++) e[q] = ew[k + q];
        ushort4 hv[8];
#pragma unroll
        for (int q = 0; q < 8; q++) hv[q] = *(const ushort4*)(hb + (size_t)e[q].x * 1024);
#pragma unroll
        for (int q = 0; q < 8; q++) {
            float u = __int_as_float(e[q].y);
            a0 += u * bf2f(hv[q].x); a1 += u * bf2f(hv[q].y);
            a2 += u * bf2f(hv[q].z); a3 += u * bf2f(hv[q].w);
        }
    }
    if (k + 4 <= cnt) {
        int2 e[4];
#pragma unroll
        for (int q = 0; q < 4; q++) e[q] = ew[k + q];
        ushort4 hv[4];
#pragma unroll
        for (int q = 0; q < 4; q++) hv[q] = *(const ushort4*)(hb + (size_t)e[q].x * 1024);
#pragma unroll
        for (int q = 0; q < 4; q++) {
            float u = __int_as_float(e[q].y);
            a0 += u * bf2f(hv[q].x); a1 += u * bf2f(hv[q].y);
            a2 += u * bf2f(hv[q].z); a3 += u * bf2f(hv[q].w);
        }
        k += 4;
    }
    int rem = cnt - k;  // 0..3
    if (rem > 0) {
        int2 e[3];
#pragma unroll
        for (int q = 0; q < 3; q++) {
            int kk = k + q; if (kk > cnt - 1) kk = cnt - 1;
            e[q] = ew[kk];
        }
        ushort4 hv[3];
#pragma unroll
        for (int q = 0; q < 3; q++) hv[q] = *(const ushort4*)(hb + (size_t)e[q].x * 1024);
        float u0 = __int_as_float(e[0].y);
        float u1 = rem > 1 ? __int_as_float(e[1].y) : 0.f;
        float u2 = rem > 2 ? __int_as_float(e[2].y) : 0.f;
        a0 += u0 * bf2f(hv[0].x) + u1 * bf2f(hv[1].x) + u2 * bf2f(hv[2].x);
        a1 += u0 * bf2f(hv[0].y) + u1 * bf2f(hv[1].y) + u2 * bf2f(hv[2].y);
        a2 += u0 * bf2f(hv[0].z) + u1 * bf2f(hv[1].z) + u2 * bf2f(hv[2].z);
        a3 += u0 * bf2f(hv[0].w) + u1 * bf2f(hv[1].w) + u2 * bf2f(hv[2].w);
    }
    float wi = rs_i[node];
    u16x4 o;
    o.x = f2bf(a0 * wi); o.y = f2bf(a1 * wi);
    o.z = f2bf(a2 * wi); o.w = f2bf(a3 * wi);
    __builtin_nontemporal_store(o, (u16x4*)(hcat + (size_t)node * 1024 + 256 * (r + 1) + lane * 4));
}

// ---------------------------------------------------------------------------
// bf16 MFMA GEMM — R2-verified 2-sync K-loop + LDS-staged C epilogue
// (best measured: 117.7 us @ K=1024, FETCH 104 MB, WRITE 55 MB).
// ---------------------------------------------------------------------------
__global__ __launch_bounds__(512, 4) void mfma_gemm(const unsigned short* __restrict__ A, int ldA,
                                                    const unsigned short* __restrict__ Bt,
                                                    const float* __restrict__ bias,
                                                    void* __restrict__ Cv, int ldC,
                                                    int Nstore, int K, int c_bf16,
                                                    float* __restrict__ stats) {
    __shared__ unsigned short lds[33792];   // 66 KB
    int tid = threadIdx.x;
    int w = tid >> 6, lane = tid & 63;
    int quad = lane >> 4, lr = lane & 15;
    int bm = blockIdx.y * 128;
    int wm = w >> 2, wn = w & 3;        // 2x4 wave grid, 64x64 C-tile per wave
    int lrow = lane >> 2;
    int lslot = lane & 3;

    f32x4 acc[4][4];
#pragma unroll
    for (int i = 0; i < 4; i++)
#pragma unroll
        for (int j = 0; j < 4; j++) acc[i][j] = (f32x4){0.f, 0.f, 0.f, 0.f};

    for (int k0 = 0; k0 < K; k0 += 64) {
        int rA = w * 16 + lrow;
        int cgA = lslot ^ ((rA >> 1) & 3);
#pragma unroll
        for (int h = 0; h < 2; h++) {
            gl_lds16(A + (size_t)(bm + rA) * ldA + k0 + h * 32 + cgA * 8,
                     &lds[h * 4096 + w * 512]);
#pragma unroll
            for (int c = 0; c < 2; c++) {
                int cc = w * 2 + c;
                int rB = cc * 16 + lrow;
                int cgB = lslot ^ ((rB >> 1) & 3);
                gl_lds16(Bt + (size_t)rB * K + k0 + h * 32 + cgB * 8,
                         &lds[8192 + h * 8192 + cc * 512]);
            }
        }
        __syncthreads();
#pragma unroll
        for (int h = 0; h < 2; h++) {
            bf16x8 af[4], bfr[4];
#pragma unroll
            for (int i = 0; i < 4; i++) {
                int r = wm * 64 + i * 16 + lr;
                int s = quad ^ ((r >> 1) & 3);
                af[i] = *(const bf16x8*)&lds[h * 4096 + r * 32 + s * 8];
            }
#pragma unroll
            for (int j = 0; j < 4; j++) {
                int n = wn * 64 + j * 16 + lr;
                int s = quad ^ ((n >> 1) & 3);
                bfr[j] = *(const bf16x8*)&lds[8192 + h * 8192 + n * 32 + s * 8];
            }
#pragma unroll
            for (int i = 0; i < 4; i++)
#pragma unroll
                for (int j = 0; j < 4; j++)
                    acc[i][j] = __builtin_amdgcn_mfma_f32_16x16x32_bf16(af[i], bfr[j], acc[i][j], 0, 0, 0);
        }
        __syncthreads();
    }

    if (c_bf16) {
        unsigned short* ldsC = lds;    // [128][264] padded stride
#pragma unroll
        for (int j = 0; j < 4; j++) {
            int col = wn * 64 + j * 16 + lr;
            float bv = bias ? bias[col] : 0.f;
            float ssum = 0.f, ssq = 0.f;
#pragma unroll
            for (int i = 0; i < 4; i++) {
#pragma unroll
                for (int v = 0; v < 4; v++) {
                    int row = wm * 64 + i * 16 + quad * 4 + v;
                    float val = acc[i][j][v] + bv;
                    ldsC[row * 264 + col] = f2bf(val);
                    if (bm + row < NN) { ssum += val; ssq += val * val; }
                }
            }
            if (stats) {
                ssum += __shfl_xor(ssum, 16); ssum += __shfl_xor(ssum, 32);
                ssq  += __shfl_xor(ssq, 16);  ssq  += __shfl_xor(ssq, 32);
                if (quad == 0) {
                    atomicAdd(&stats[col], ssum);
                    atomicAdd(&stats[HH + col], ssq);
                }
            }
        }
        __syncthreads();
        int row = tid >> 2, seg = tid & 3;
        if (bm + row < NN) {
            const unsigned short* srcp = ldsC + row * 264 + seg * 64;
            unsigned short* dstp = (unsigned short*)Cv + (size_t)(bm + row) * ldC + seg * 64;
#pragma unroll
            for (int q = 0; q < 8; q++)
                *(uint4*)(dstp + q * 8) = *(const uint4*)(srcp + q * 8);
        }
    } else {
        float* Cf = (float*)Cv;
#pragma unroll
        for (int j = 0; j < 4; j++) {
            int col = wn * 64 + j * 16 + lr;
            if (col >= Nstore) continue;
            float bv = bias ? bias[col] : 0.f;
#pragma unroll
            for (int i = 0; i < 4; i++) {
#pragma unroll
                for (int v = 0; v < 4; v++) {
                    int row = bm + wm * 64 + i * 16 + quad * 4 + v;
                    if (row < NN) Cf[(size_t)row * ldC + col] = acc[i][j][v] + bv;
                }
            }
        }
    }
}

// ---------------------------------------------------------------------------
// BN: coef precompute + vectorized apply (bf16 in, bf16 out at ld=1024)
// ---------------------------------------------------------------------------
__global__ void bn_coef(const float* __restrict__ stats, const float* __restrict__ g,
                        const float* __restrict__ b, float* __restrict__ coef, float invM) {
    int c = threadIdx.x;
    float mean = stats[c] * invM;
    float var = stats[HH + c] * invM - mean * mean;
    float inv = rsqrtf(var + 1e-5f);
    float sc = g[c] * inv;
    coef[c] = sc;
    coef[HH + c] = b[c] - mean * sc;
}

// act: 1 = relu, 2 = leaky relu (0.01)
__global__ __launch_bounds__(256) void bn_apply_v(const unsigned short* __restrict__ Z,
                                                  const float* __restrict__ coef,
                                                  unsigned short* __restrict__ out, int act) {
    int idx = blockIdx.x * blockDim.x + threadIdx.x;
    if (idx >= NN * 32) return;
    int row = idx >> 5, cg = (idx & 31) * 8;
    union { uint4 u; unsigned short s[8]; } zin, zo;
    zin.u = *(const uint4*)(Z + (size_t)row * HH + cg);
    f32x4 sc0 = *(const f32x4*)(coef + cg);
    f32x4 sc1 = *(const f32x4*)(coef + cg + 4);
    f32x4 sh0 = *(const f32x4*)(coef + HH + cg);
    f32x4 sh1 = *(const f32x4*)(coef + HH + cg + 4);
#pragma unroll
    for (int j = 0; j < 8; j++) {
        float sc = (j < 4) ? sc0[j] : sc1[j - 4];
        float sh = (j < 4) ? sh0[j] : sh1[j - 4];
        float v = bf2f(zin.s[j]) * sc + sh;
        if (act == 1) v = fmaxf(v, 0.f);
        else v = (v < 0.f) ? 0.01f * v : v;
        zo.s[j] = f2bf(v);
    }
    *(uint4*)(out + (size_t)row * 1024 + cg) = zo.u;
}

// ---------------------------------------------------------------------------
extern "C" void kernel_launch(void* const* d_in, const int* in_sizes, int n_in,
                              void* d_out, int out_size, void* d_ws, size_t ws_size,
                              hipStream_t stream) {
    const float* x        = (const float*)d_in[0];
    const int*   esrc     = (const int*)d_in[1];
    const int*   edst     = (const int*)d_in[2];
    const float* W_feat   = (const float*)d_in[3];
    const float* b_feat   = (const float*)d_in[4];
    const float* g_feat   = (const float*)d_in[5];
    const float* beta_feat= (const float*)d_in[6];
    const float* gcn_W    = (const float*)d_in[7];
    const float* gcn_b    = (const float*)d_in[8];
    const float* skip_W   = (const float*)d_in[9];
    const float* skip_b   = (const float*)d_in[10];
    const float* bn_g     = (const float*)d_in[11];
    const float* bn_b     = (const float*)d_in[12];
    const float* W_c1     = (const float*)d_in[13];
    const float* b_c1     = (const float*)d_in[14];
    const float* g_c      = (const float*)d_in[15];
    const float* beta_c   = (const float*)d_in[16];
    const float* W_c2     = (const float*)d_in[17];
    const float* b_c2     = (const float*)d_in[18];
    float* out = (float*)d_out;
    (void)in_sizes; (void)n_in; (void)out_size; (void)ws_size;

    char* w = (char*)d_ws;
    size_t off = 0;
    auto alloc = [&](size_t bytes) { void* p = w + off; off += (bytes + 255) & ~(size_t)255; return p; };
    unsigned short* hcat = (unsigned short*)alloc((size_t)MPAD * 1024 * 2);
    unsigned short* xpad = hcat;  // [MPAD][320] bf16, dead after feat GEMM
    unsigned short* c_acc = (unsigned short*)alloc((size_t)NN * HH * 2);  // bf16 pre-BN C
    float* f_stats = (float*)alloc(4 * 2 * HH * 4);   // 4 slices of [2][HH]
    float* f_coef  = (float*)alloc(2 * HH * 4);
    float* f_rs_out = (float*)alloc((size_t)RR * NN * 4);
    float* f_rs_in  = (float*)alloc((size_t)RR * NN * 4);
    int* i_cnt_out = (int*)alloc((size_t)RR * NN * 4);
    int* i_cnt_in  = (int*)alloc((size_t)RR * NN * 4);
    int* i_off     = (int*)alloc((size_t)RR * (NN + 1) * 4);
    int* i_cnts    = (int*)alloc((size_t)ES * RR * NN * 4);   // 30 MB slice counts/bases
    int2* i_srcw   = (int2*)alloc((size_t)RR * EE * 8);
    int* i_bsum    = (int*)alloc((size_t)RR * SNB * 4);
    unsigned short* Bt_feat = (unsigned short*)alloc(256 * 320 * 2);
    unsigned short* Bt_l0   = (unsigned short*)alloc(256 * 1024 * 2);
    unsigned short* Bt_l1   = (unsigned short*)alloc(256 * 1024 * 2);
    unsigned short* Bt_c1   = (unsigned short*)alloc(256 * 256 * 2);
    unsigned short* Bt_c2   = (unsigned short*)alloc(256 * 256 * 2);  // padded to 256 rows
    float* bias_l0 = (float*)alloc(HH * 4);
    float* bias_l1 = (float*)alloc(HH * 4);

    const float invM = 1.0f / (float)NN;

    // --- CSR + degrees (LDS-chunked, edge-slice parallel) ---
    (void)hipMemsetAsync(i_cnt_out, 0, (size_t)RR * NN * 4, stream);
    (void)hipMemsetAsync(f_stats, 0, 4 * 2 * HH * 4, stream);
    hist_out<<<dim3(NCHUNK, RR, 4), 256, 0, stream>>>(esrc, i_cnt_out);
    hist_slice<<<dim3(NCHUNK, RR, ES), 256, 0, stream>>>(edst, i_cnts);
    sum_slices<<<cdiv_h(RR * NN, 256), 256, 0, stream>>>(i_cnts, i_cnt_in);
    rs_kernel<<<cdiv_h(RR * NN, 256), 256, 0, stream>>>(i_cnt_out, i_cnt_in, f_rs_out, f_rs_in, RR * NN);
    scan_a<<<dim3(SNB, RR), 256, 0, stream>>>(i_cnt_in, i_bsum);
    scan_b<<<1, 64, 0, stream>>>(i_bsum, i_off);
    scan_c<<<dim3(SNB, RR), 256, 0, stream>>>(i_cnt_in, i_bsum, i_off);
    prefix_slices<<<cdiv_h(RR * NN, 256), 256, 0, stream>>>(i_off, i_cnts);
    fill_sliced<<<dim3(NCHUNK, RR, ES), 256, 0, stream>>>(esrc, edst, f_rs_out, i_cnts, i_srcw);

    // --- weight prep (bf16, transposed) ---
    convert_x<<<cdiv_h(MPAD * 80, 256), 256, 0, stream>>>(x, xpad);
    wprep_feat<<<256, 320, 0, stream>>>(W_feat, Bt_feat);
    wprep_layer<<<1024, 256, 0, stream>>>(skip_W, gcn_W, Bt_l0);
    wprep_layer<<<1024, 256, 0, stream>>>(skip_W + (size_t)HH * HH, gcn_W + (size_t)RR * HH * HH, Bt_l1);
    bias_layer<<<1, 256, 0, stream>>>(skip_b, gcn_b, bias_l0);
    bias_layer<<<1, 256, 0, stream>>>(skip_b + HH, gcn_b + (size_t)RR * HH, bias_l1);
    wprep_c1<<<256, 256, 0, stream>>>(W_c1, Bt_c1);
    wprep_c2<<<256, 256, 0, stream>>>(W_c2, Bt_c2);

    dim3 grid_G(1, MPAD / 128);   // BN=256 covers the full N in one tile column
    dim3 grid_A(cdiv_h(NN, 4), RR);
    const int nblk_a = cdiv_h(NN * 32, 256);
    float* st0 = f_stats;
    float* st1 = f_stats + 2 * HH;
    float* st2 = f_stats + 4 * HH;
    float* st3 = f_stats + 6 * HH;

    // --- feat_reduce: h = relu(BN(x @ W_feat + b_feat)) -> hcat[:,0:256] bf16 ---
    mfma_gemm<<<grid_G, 512, 0, stream>>>(xpad, 320, Bt_feat, b_feat, c_acc, HH, HH, 320, 1, st0);
    bn_coef<<<1, 256, 0, stream>>>(st0, g_feat, beta_feat, f_coef, invM);
    bn_apply_v<<<nblk_a, 256, 0, stream>>>(c_acc, f_coef, hcat, 1);

    // --- GCN layers: one K=1024 GEMM per layer ---
    for (int l = 0; l < LL; l++) {
        agg_bf16<<<grid_A, 256, 0, stream>>>(hcat, i_off, i_srcw, f_rs_in);
        float* st = l ? st2 : st1;
        mfma_gemm<<<grid_G, 512, 0, stream>>>(hcat, 1024, l ? Bt_l1 : Bt_l0,
                                              l ? bias_l1 : bias_l0, c_acc, HH, HH, 1024, 1, st);
        bn_coef<<<1, 256, 0, stream>>>(st, bn_g + (size_t)l * HH, bn_b + (size_t)l * HH, f_coef, invM);
        bn_apply_v<<<nblk_a, 256, 0, stream>>>(c_acc, f_coef, hcat, 2);
    }

    // --- head ---
    mfma_gemm<<<grid_G, 512, 0, stream>>>(hcat, 1024, Bt_c1, b_c1, c_acc, HH, HH, 256, 1, st3);
    bn_coef<<<1, 256, 0, stream>>>(st3, g_c, beta_c, f_coef, invM);
    bn_apply_v<<<nblk_a, 256, 0, stream>>>(c_acc, f_coef, hcat + 256, 1);
    mfma_gemm<<<grid_G, 512, 0, stream>>>(hcat + 256, 1024, Bt_c2, b_c2, out, CC, CC, 256, 0, nullptr);
}

// Round 9
// 1164.313 us; speedup vs baseline: 1.6299x; 1.0059x over previous
//
#include <hip/hip_runtime.h>

#define NN 100000   // nodes
#define EE 500000   // edges per relation
#define RR 3        // relations
#define LL 2        // layers
#define FF 300      // input features
#define HH 256      // hidden
#define CC 23       // classes
#define MPAD 100096 // 782 * 128 (also divisible by 64: 1564 * 64)
#define SCHUNK 2048
#define SNB ((NN + SCHUNK - 1) / SCHUNK)   // 49
#define CH 16384    // node-chunk for LDS hist/fill (64 KB LDS)
#define NCHUNK 7    // ceil(NN / CH)
#define ES 25       // edge slices (EE/ES = 20000 edges, 5000 int4 per slice)
#define EES4 (EE / ES / 4)   // 5000

static inline int cdiv_h(int a, int b) { return (a + b - 1) / b; }

typedef __attribute__((ext_vector_type(8))) short bf16x8;
typedef __attribute__((ext_vector_type(4))) float f32x4;
typedef __attribute__((ext_vector_type(4))) unsigned short u16x4;

__device__ inline unsigned short f2bf(float f) {
    union { float f; unsigned int u; } v; v.f = f;
    unsigned int r = v.u + 0x7fff + ((v.u >> 16) & 1);
    return (unsigned short)(r >> 16);
}
__device__ inline float bf2f(unsigned short u) {
    union { unsigned int u; float f; } v; v.u = ((unsigned int)u) << 16;
    return v.f;
}
__device__ inline void gl_lds16(const void* g, void* l) {
    __builtin_amdgcn_global_load_lds((const __attribute__((address_space(1))) unsigned int*)g,
                                     (__attribute__((address_space(3))) unsigned int*)l,
                                     16, 0, 0);
}

// ---------------------------------------------------------------------------
// CSR build — LDS-chunked with edge-slice parallelism (R7-verified).
// ---------------------------------------------------------------------------
__global__ __launch_bounds__(256) void hist_out(const int* __restrict__ esrc,
                                                int* __restrict__ cnt_out) {
    __shared__ unsigned int h[CH];
    int chunk = blockIdx.x, r = blockIdx.y, es = blockIdx.z;
    const int* ids = esrc + (size_t)r * EE;
    int* cnt = cnt_out + (size_t)r * NN;
    int base = chunk * CH;
    for (int j = threadIdx.x; j < CH; j += 256) h[j] = 0;
    __syncthreads();
    const int lo4 = es * (EE / 4 / 4), hi4 = lo4 + EE / 4 / 4;
    const int4* ids4 = (const int4*)ids;
    for (int i = lo4 + threadIdx.x; i < hi4; i += 256) {
        int4 v = ids4[i];
        unsigned o0 = (unsigned)(v.x - base), o1 = (unsigned)(v.y - base);
        unsigned o2 = (unsigned)(v.z - base), o3 = (unsigned)(v.w - base);
        if (o0 < CH) atomicAdd(&h[o0], 1u);
        if (o1 < CH) atomicAdd(&h[o1], 1u);
        if (o2 < CH) atomicAdd(&h[o2], 1u);
        if (o3 < CH) atomicAdd(&h[o3], 1u);
    }
    __syncthreads();
    for (int j = threadIdx.x; j < CH; j += 256) {
        unsigned v = h[j];
        int idx = base + j;
        if (v && idx < NN) atomicAdd(&cnt[idx], (int)v);
    }
}

// Per-slice in-degree counts: grid (NCHUNK, RR, ES). Single writer per
// (s,r,n) -> plain stores, no global atomics. cnt_s[((s*RR)+r)*NN + n].
__global__ __launch_bounds__(256) void hist_slice(const int* __restrict__ edst,
                                                  int* __restrict__ cnt_s) {
    __shared__ unsigned int h[CH];
    int chunk = blockIdx.x, r = blockIdx.y, s = blockIdx.z;
    int base = chunk * CH;
    for (int j = threadIdx.x; j < CH; j += 256) h[j] = 0;
    __syncthreads();
    const int4* d4p = (const int4*)(edst + (size_t)r * EE);
    const int lo = s * EES4, hi = lo + EES4;
    for (int i = lo + threadIdx.x; i < hi; i += 256) {
        int4 v = d4p[i];
        unsigned o0 = (unsigned)(v.x - base), o1 = (unsigned)(v.y - base);
        unsigned o2 = (unsigned)(v.z - base), o3 = (unsigned)(v.w - base);
        if (o0 < CH) atomicAdd(&h[o0], 1u);
        if (o1 < CH) atomicAdd(&h[o1], 1u);
        if (o2 < CH) atomicAdd(&h[o2], 1u);
        if (o3 < CH) atomicAdd(&h[o3], 1u);
    }
    __syncthreads();
    int* dst = cnt_s + ((size_t)s * RR + r) * NN;
    for (int j = threadIdx.x; j < CH; j += 256) {
        int idx = base + j;
        if (idx < NN) dst[idx] = (int)h[j];
    }
}

// cnt_in[r][n] = sum_s cnt_s[s][r][n]
__global__ void sum_slices(const int* __restrict__ cnt_s, int* __restrict__ cnt_in) {
    int i = blockIdx.x * blockDim.x + threadIdx.x;
    if (i >= RR * NN) return;
    int r = i / NN, n = i - r * NN;
    int sum = 0;
#pragma unroll 5
    for (int s = 0; s < ES; s++) sum += cnt_s[((size_t)s * RR + r) * NN + n];
    cnt_in[i] = sum;
}

__global__ void rs_kernel(const int* __restrict__ cnt_out, const int* __restrict__ cnt_in,
                          float* __restrict__ rs_out, float* __restrict__ rs_in, int total) {
    int i = blockIdx.x * blockDim.x + threadIdx.x;
    if (i >= total) return;
    rs_out[i] = rsqrtf(fmaxf((float)cnt_out[i], 1.0f));
    rs_in[i]  = rsqrtf(fmaxf((float)cnt_in[i], 1.0f));
}

// --- 3-phase exclusive scan of in-degree counts -> CSR offsets ---
__global__ __launch_bounds__(256) void scan_a(const int* __restrict__ cnt, int* __restrict__ bsum) {
    int r = blockIdx.y, b = blockIdx.x, t = threadIdx.x;
    const int* c = cnt + (size_t)r * NN;
    int base = b * SCHUNK;
    int s = 0;
    for (int i = t; i < SCHUNK; i += 256) {
        int idx = base + i;
        if (idx < NN) s += c[idx];
    }
#pragma unroll
    for (int o = 1; o < 64; o <<= 1) s += __shfl_xor(s, o);
    __shared__ int sh[4];
    if ((t & 63) == 0) sh[t >> 6] = s;
    __syncthreads();
    if (t == 0) bsum[r * SNB + b] = sh[0] + sh[1] + sh[2] + sh[3];
}

__global__ void scan_b(int* __restrict__ bsum, int* __restrict__ offs) {
    int r = threadIdx.x;
    if (r >= RR) return;
    int* bs = bsum + r * SNB;
    int run = 0;
    for (int i = 0; i < SNB; i++) { int v = bs[i]; bs[i] = run; run += v; }
    offs[(size_t)r * (NN + 1) + NN] = run;
}

__global__ __launch_bounds__(256) void scan_c(const int* __restrict__ cnt, const int* __restrict__ bsum,
                                              int* __restrict__ offs) {
    int r = blockIdx.y, b = blockIdx.x, t = threadIdx.x;
    const int* c = cnt + (size_t)r * NN;
    int base = b * SCHUNK + t * 8;
    int v[8]; int s = 0;
#pragma unroll
    for (int j = 0; j < 8; j++) {
        int idx = base + j;
        v[j] = (idx < NN) ? c[idx] : 0;
        s += v[j];
    }
    __shared__ int sh[256];
    sh[t] = s;
    __syncthreads();
    for (int d = 1; d < 256; d <<= 1) {
        int x = (t >= d) ? sh[t - d] : 0;
        __syncthreads();
        sh[t] += x;
        __syncthreads();
    }
    int run = sh[t] - s + bsum[r * SNB + b];
    int* orow = offs + (size_t)r * (NN + 1);
#pragma unroll
    for (int j = 0; j < 8; j++) {
        int idx = base + j;
        if (idx < NN) orow[idx] = run;
        run += v[j];
    }
}

// In-place exclusive scan of cnt_s over s per (r,n): cnt_s becomes per-slice
// cursor base. Must run AFTER sum_slices and scan.
__global__ void prefix_slices(const int* __restrict__ offs_all, int* __restrict__ cnt_s) {
    int i = blockIdx.x * blockDim.x + threadIdx.x;
    if (i >= RR * NN) return;
    int r = i / NN, n = i - r * NN;
    int base = offs_all[(size_t)r * (NN + 1) + n];
    for (int s = 0; s < ES; s++) {
        size_t idx = ((size_t)s * RR + r) * NN + n;
        int c = cnt_s[idx];
        cnt_s[idx] = base;
        base += c;
    }
}

// Fill packed edge stream: grid (NCHUNK, RR, ES) = 525 blocks. LDS cursors
// seeded from per-slice bases; each block touches only its 20K-edge slice.
__global__ __launch_bounds__(256) void fill_sliced(const int* __restrict__ esrc,
                                                   const int* __restrict__ edst,
                                                   const float* __restrict__ rs_out,
                                                   const int* __restrict__ posbase,
                                                   int2* __restrict__ srcw) {
    __shared__ int curL[CH];
    int chunk = blockIdx.x, r = blockIdx.y, s = blockIdx.z;
    int base = chunk * CH;
    const int* pb = posbase + ((size_t)s * RR + r) * NN;
    for (int j = threadIdx.x; j < CH; j += 256) {
        int idx = base + j;
        curL[j] = (idx < NN) ? pb[idx] : 0;
    }
    __syncthreads();
    const int4* s4p = (const int4*)(esrc + (size_t)r * EE);
    const int4* d4p = (const int4*)(edst + (size_t)r * EE);
    const float* rso = rs_out + (size_t)r * NN;
    int2* out = srcw + (size_t)r * EE;
    const int lo = s * EES4, hi = lo + EES4;
    for (int i = lo + threadIdx.x; i < hi; i += 256) {
        int4 d4 = d4p[i];
        int4 s4 = s4p[i];
#pragma unroll
        for (int q = 0; q < 4; q++) {
            int d = (q == 0) ? d4.x : (q == 1) ? d4.y : (q == 2) ? d4.z : d4.w;
            unsigned o = (unsigned)(d - base);
            if (o < CH) {
                int sv = (q == 0) ? s4.x : (q == 1) ? s4.y : (q == 2) ? s4.z : s4.w;
                int pos = atomicAdd(&curL[o], 1);
                out[pos] = make_int2(sv, __float_as_int(rso[sv]));
            }
        }
    }
}

// ---------------------------------------------------------------------------
// Weight prep: fp32 -> bf16, transposed to n-major [Ncols][K]
// ---------------------------------------------------------------------------
__global__ __launch_bounds__(256) void convert_x(const float* __restrict__ x, unsigned short* __restrict__ xpad) {
    int idx = blockIdx.x * blockDim.x + threadIdx.x;   // over MPAD*80
    if (idx >= MPAD * 80) return;
    int row = idx / 80, c4 = (idx - row * 80) * 4;
    ushort4 o;
    if (row < NN && c4 + 3 < FF) {   // FF % 4 == 0
        float4 v = *(const float4*)(x + (size_t)row * FF + c4);
        o.x = f2bf(v.x); o.y = f2bf(v.y); o.z = f2bf(v.z); o.w = f2bf(v.w);
    } else {
        o.x = 0; o.y = 0; o.z = 0; o.w = 0;
    }
    *(ushort4*)(xpad + (size_t)row * 320 + c4) = o;
}

__global__ void wprep_feat(const float* __restrict__ W, unsigned short* __restrict__ Bt) {
    int n = blockIdx.x;
    int k = threadIdx.x;
    float v = (k < FF) ? W[(size_t)k * HH + n] : 0.f;
    Bt[(size_t)n * 320 + k] = f2bf(v);
}

__global__ void wprep_layer(const float* __restrict__ skipW, const float* __restrict__ gcnW,
                            unsigned short* __restrict__ Bt) {
    int idx = blockIdx.x * blockDim.x + threadIdx.x;
    int n = idx >> 10, k = idx & 1023;
    int seg = k >> 8, k2 = k & 255;
    float v = (seg == 0) ? skipW[(size_t)k2 * HH + n]
                         : gcnW[(size_t)(seg - 1) * HH * HH + (size_t)k2 * HH + n] * (1.0f / 3.0f);
    Bt[(size_t)n * 1024 + k] = f2bf(v);
}

__global__ void bias_layer(const float* __restrict__ skip_b, const float* __restrict__ gcn_b,
                           float* __restrict__ bias) {
    int t = threadIdx.x;
    bias[t] = skip_b[t] + (gcn_b[t] + gcn_b[HH + t] + gcn_b[2 * HH + t]) * (1.0f / 3.0f);
}

__global__ void wprep_c1(const float* __restrict__ W, unsigned short* __restrict__ Bt) {
    int idx = blockIdx.x * blockDim.x + threadIdx.x;
    int n = idx >> 8, k = idx & 255;
    Bt[(size_t)n * HH + k] = f2bf(W[(size_t)k * HH + n]);
}

__global__ void wprep_c2(const float* __restrict__ W, unsigned short* __restrict__ Bt) {
    int n = blockIdx.x;   // 0..255 (rows >= CC zero-padded for the 256-wide N tile)
    int k = threadIdx.x;
    float v = (n < CC) ? W[(size_t)k * CC + n] : 0.f;
    Bt[(size_t)n * HH + k] = f2bf(v);
}

// ---------------------------------------------------------------------------
// Aggregation (bf16), full-width (R2-verified, untouched): grid (NN/4, RR).
// ---------------------------------------------------------------------------
__global__ __launch_bounds__(256) void agg_bf16(unsigned short* __restrict__ hcat,
                                                const int* __restrict__ offs_all,
                                                const int2* __restrict__ srcw_all,
                                                const float* __restrict__ rs_in_all) {
    int r = blockIdx.y;
    const int* offs = offs_all + (size_t)r * (NN + 1);
    const int2* srcw = srcw_all + (size_t)r * EE;
    const float* rs_i = rs_in_all + (size_t)r * NN;
    int wave = threadIdx.x >> 6;
    int lane = threadIdx.x & 63;
    int node = blockIdx.x * 4 + wave;
    if (node >= NN) return;
    int s0 = __builtin_amdgcn_readfirstlane(offs[node]);
    int s1 = __builtin_amdgcn_readfirstlane(offs[node + 1]);
    int cnt = s1 - s0;
    const int2* ew = srcw + s0;
    const unsigned short* hb = hcat + lane * 4;
    float a0 = 0.f, a1 = 0.f, a2 = 0.f, a3 = 0.f;
    int k = 0;
    for (; k + 8 <= cnt; k += 8) {
        int2 e[8];
#pragma unroll
        for (int q = 0; q < 8; q++) e[q] = ew[k + q];
        ushort4 hv[8];
#pragma unroll
        for (int q = 0; q < 8; q++) hv[q] = *(const ushort4*)(hb + (size_t)e[q].x * 1024);
#pragma unroll
        for (int q = 0; q < 8; q++) {
            float u = __int_as_float(e[q].y);
            a0 += u * bf2f(hv[q].x); a1 += u * bf2f(hv[q].y);
            a2 += u * bf2f(hv[q].z); a3 += u * bf2f(hv[q].w);
        }
    }
    if (k + 4 <= cnt) {
        int2 e[4];
#pragma unroll
        for (int q = 0; q < 4; q++) e[q] = ew[k + q];
        ushort4 hv[4];
#pragma unroll
        for (int q = 0; q < 4; q++) hv[q] = *(const ushort4*)(hb + (size_t)e[q].x * 1024);
#pragma unroll
        for (int q = 0; q < 4; q++) {
            float u = __int_as_float(e[q].y);
            a0 += u * bf2f(hv[q].x); a1 += u * bf2f(hv[q].y);
            a2 += u * bf2f(hv[q].z); a3 += u * bf2f(hv[q].w);
        }
        k += 4;
    }
    int rem = cnt - k;  // 0..3
    if (rem > 0) {
        int2 e[3];
#pragma unroll
        for (int q = 0; q < 3; q++) {
            int kk = k + q; if (kk > cnt - 1) kk = cnt - 1;
            e[q] = ew[kk];
        }
        ushort4 hv[3];
#pragma unroll
        for (int q = 0; q < 3; q++) hv[q] = *(const ushort4*)(hb + (size_t)e[q].x * 1024);
        float u0 = __int_as_float(e[0].y);
        float u1 = rem > 1 ? __int_as_float(e[1].y) : 0.f;
        float u2 = rem > 2 ? __int_as_float(e[2].y) : 0.f;
        a0 += u0 * bf2f(hv[0].x) + u1 * bf2f(hv[1].x) + u2 * bf2f(hv[2].x);
        a1 += u0 * bf2f(hv[0].y) + u1 * bf2f(hv[1].y) + u2 * bf2f(hv[2].y);
        a2 += u0 * bf2f(hv[0].z) + u1 * bf2f(hv[1].z) + u2 * bf2f(hv[2].z);
        a3 += u0 * bf2f(hv[0].w) + u1 * bf2f(hv[1].w) + u2 * bf2f(hv[2].w);
    }
    float wi = rs_i[node];
    u16x4 o;
    o.x = f2bf(a0 * wi); o.y = f2bf(a1 * wi);
    o.z = f2bf(a2 * wi); o.w = f2bf(a3 * wi);
    __builtin_nontemporal_store(o, (u16x4*)(hcat + (size_t)node * 1024 + 256 * (r + 1) + lane * 4));
}

// ---------------------------------------------------------------------------
// bf16 MFMA GEMM — same verified 2-sync K-loop + LDS-staged C epilogue,
// retiled BM=64 x BN=256 (256 thr / 4 waves, wave w owns cols w*64..w*64+63).
// LDS 40 KB -> 4 blocks/CU (vs 2 at BM=128/66KB): grid 1564 nearly all
// resident, doubling per-CU staging pipelines that overlap barrier stalls
// (GEMM was at 1.39 TB/s / 17% MfmaUtil: concurrency-starved, not BW/MFMA).
// ---------------------------------------------------------------------------
__global__ __launch_bounds__(256, 4) void mfma_gemm(const unsigned short* __restrict__ A, int ldA,
                                                    const unsigned short* __restrict__ Bt,
                                                    const float* __restrict__ bias,
                                                    void* __restrict__ Cv, int ldC,
                                                    int Nstore, int K, int c_bf16,
                                                    float* __restrict__ stats) {
    // K-loop: A half h at [h*2048] (64x32), B half h at [4096 + h*8192] (256x32).
    // Epilogue reuses lds as C[64][264] = 16896 shorts <= 20480.
    __shared__ unsigned short lds[20480];   // 40 KB
    int tid = threadIdx.x;
    int w = tid >> 6, lane = tid & 63;      // w in 0..3
    int quad = lane >> 4, lr = lane & 15;
    int bm = blockIdx.y * 64;
    int wn = w;                              // 1x4 wave grid, 64x64 C-tile per wave
    int lrow = lane >> 2;
    int lslot = lane & 3;

    f32x4 acc[4][4];
#pragma unroll
    for (int i = 0; i < 4; i++)
#pragma unroll
        for (int j = 0; j < 4; j++) acc[i][j] = (f32x4){0.f, 0.f, 0.f, 0.f};

    for (int k0 = 0; k0 < K; k0 += 64) {
        // Stage one K-tile: A 64x64 (1 load/thread/half), B 256x64 (4/half).
        int rA = w * 16 + lrow;
        int cgA = lslot ^ ((rA >> 1) & 3);
#pragma unroll
        for (int h = 0; h < 2; h++) {
            gl_lds16(A + (size_t)(bm + rA) * ldA + k0 + h * 32 + cgA * 8,
                     &lds[h * 2048 + w * 512]);
#pragma unroll
            for (int c = 0; c < 4; c++) {
                int cc = w * 4 + c;
                int rB = cc * 16 + lrow;
                int cgB = lslot ^ ((rB >> 1) & 3);
                gl_lds16(Bt + (size_t)rB * K + k0 + h * 32 + cgB * 8,
                         &lds[4096 + h * 8192 + cc * 512]);
            }
        }
        __syncthreads();
#pragma unroll
        for (int h = 0; h < 2; h++) {
            bf16x8 af[4], bfr[4];
#pragma unroll
            for (int i = 0; i < 4; i++) {
                int r = i * 16 + lr;
                int s = quad ^ ((r >> 1) & 3);
                af[i] = *(const bf16x8*)&lds[h * 2048 + r * 32 + s * 8];
            }
#pragma unroll
            for (int j = 0; j < 4; j++) {
                int n = wn * 64 + j * 16 + lr;
                int s = quad ^ ((n >> 1) & 3);
                bfr[j] = *(const bf16x8*)&lds[4096 + h * 8192 + n * 32 + s * 8];
            }
#pragma unroll
            for (int i = 0; i < 4; i++)
#pragma unroll
                for (int j = 0; j < 4; j++)
                    acc[i][j] = __builtin_amdgcn_mfma_f32_16x16x32_bf16(af[i], bfr[j], acc[i][j], 0, 0, 0);
        }
        __syncthreads();
    }

    if (c_bf16) {
        // All c_bf16 callers store the full 256-col tile (Nstore == HH).
        unsigned short* ldsC = lds;    // [64][264] padded stride
#pragma unroll
        for (int j = 0; j < 4; j++) {
            int col = wn * 64 + j * 16 + lr;
            float bv = bias ? bias[col] : 0.f;
            float ssum = 0.f, ssq = 0.f;
#pragma unroll
            for (int i = 0; i < 4; i++) {
#pragma unroll
                for (int v = 0; v < 4; v++) {
                    int row = i * 16 + quad * 4 + v;
                    float val = acc[i][j][v] + bv;
                    ldsC[row * 264 + col] = f2bf(val);
                    if (bm + row < NN) { ssum += val; ssq += val * val; }
                }
            }
            if (stats) {
                ssum += __shfl_xor(ssum, 16); ssum += __shfl_xor(ssum, 32);
                ssq  += __shfl_xor(ssq, 16);  ssq  += __shfl_xor(ssq, 32);
                if (quad == 0) {
                    atomicAdd(&stats[col], ssum);
                    atomicAdd(&stats[HH + col], ssq);
                }
            }
        }
        __syncthreads();
        // Coalesced flush: 4 threads per row, 64 cols (128 B) each.
        int row = tid >> 2, seg = tid & 3;
        if (bm + row < NN) {
            const unsigned short* srcp = ldsC + row * 264 + seg * 64;
            unsigned short* dstp = (unsigned short*)Cv + (size_t)(bm + row) * ldC + seg * 64;
#pragma unroll
            for (int q = 0; q < 8; q++)
                *(uint4*)(dstp + q * 8) = *(const uint4*)(srcp + q * 8);
        }
    } else {
        float* Cf = (float*)Cv;
#pragma unroll
        for (int j = 0; j < 4; j++) {
            int col = wn * 64 + j * 16 + lr;
            if (col >= Nstore) continue;
            float bv = bias ? bias[col] : 0.f;
#pragma unroll
            for (int i = 0; i < 4; i++) {
#pragma unroll
                for (int v = 0; v < 4; v++) {
                    int row = bm + i * 16 + quad * 4 + v;
                    if (row < NN) Cf[(size_t)row * ldC + col] = acc[i][j][v] + bv;
                }
            }
        }
    }
}

// ---------------------------------------------------------------------------
// BN: coef precompute + vectorized apply (bf16 in, bf16 out at ld=1024)
// ---------------------------------------------------------------------------
__global__ void bn_coef(const float* __restrict__ stats, const float* __restrict__ g,
                        const float* __restrict__ b, float* __restrict__ coef, float invM) {
    int c = threadIdx.x;
    float mean = stats[c] * invM;
    float var = stats[HH + c] * invM - mean * mean;
    float inv = rsqrtf(var + 1e-5f);
    float sc = g[c] * inv;
    coef[c] = sc;
    coef[HH + c] = b[c] - mean * sc;
}

// act: 1 = relu, 2 = leaky relu (0.01)
__global__ __launch_bounds__(256) void bn_apply_v(const unsigned short* __restrict__ Z,
                                                  const float* __restrict__ coef,
                                                  unsigned short* __restrict__ out, int act) {
    int idx = blockIdx.x * blockDim.x + threadIdx.x;
    if (idx >= NN * 32) return;
    int row = idx >> 5, cg = (idx & 31) * 8;
    union { uint4 u; unsigned short s[8]; } zin, zo;
    zin.u = *(const uint4*)(Z + (size_t)row * HH + cg);
    f32x4 sc0 = *(const f32x4*)(coef + cg);
    f32x4 sc1 = *(const f32x4*)(coef + cg + 4);
    f32x4 sh0 = *(const f32x4*)(coef + HH + cg);
    f32x4 sh1 = *(const f32x4*)(coef + HH + cg + 4);
#pragma unroll
    for (int j = 0; j < 8; j++) {
        float sc = (j < 4) ? sc0[j] : sc1[j - 4];
        float sh = (j < 4) ? sh0[j] : sh1[j - 4];
        float v = bf2f(zin.s[j]) * sc + sh;
        if (act == 1) v = fmaxf(v, 0.f);
        else v = (v < 0.f) ? 0.01f * v : v;
        zo.s[j] = f2bf(v);
    }
    *(uint4*)(out + (size_t)row * 1024 + cg) = zo.u;
}

// ---------------------------------------------------------------------------
extern "C" void kernel_launch(void* const* d_in, const int* in_sizes, int n_in,
                              void* d_out, int out_size, void* d_ws, size_t ws_size,
                              hipStream_t stream) {
    const float* x        = (const float*)d_in[0];
    const int*   esrc     = (const int*)d_in[1];
    const int*   edst     = (const int*)d_in[2];
    const float* W_feat   = (const float*)d_in[3];
    const float* b_feat   = (const float*)d_in[4];
    const float* g_feat   = (const float*)d_in[5];
    const float* beta_feat= (const float*)d_in[6];
    const float* gcn_W    = (const float*)d_in[7];
    const float* gcn_b    = (const float*)d_in[8];
    const float* skip_W   = (const float*)d_in[9];
    const float* skip_b   = (const float*)d_in[10];
    const float* bn_g     = (const float*)d_in[11];
    const float* bn_b     = (const float*)d_in[12];
    const float* W_c1     = (const float*)d_in[13];
    const float* b_c1     = (const float*)d_in[14];
    const float* g_c      = (const float*)d_in[15];
    const float* beta_c   = (const float*)d_in[16];
    const float* W_c2     = (const float*)d_in[17];
    const float* b_c2     = (const float*)d_in[18];
    float* out = (float*)d_out;
    (void)in_sizes; (void)n_in; (void)out_size; (void)ws_size;

    char* w = (char*)d_ws;
    size_t off = 0;
    auto alloc = [&](size_t bytes) { void* p = w + off; off += (bytes + 255) & ~(size_t)255; return p; };
    unsigned short* hcat = (unsigned short*)alloc((size_t)MPAD * 1024 * 2);
    unsigned short* xpad = hcat;  // [MPAD][320] bf16, dead after feat GEMM
    unsigned short* c_acc = (unsigned short*)alloc((size_t)NN * HH * 2);  // bf16 pre-BN C
    float* f_stats = (float*)alloc(4 * 2 * HH * 4);   // 4 slices of [2][HH]
    float* f_coef  = (float*)alloc(2 * HH * 4);
    float* f_rs_out = (float*)alloc((size_t)RR * NN * 4);
    float* f_rs_in  = (float*)alloc((size_t)RR * NN * 4);
    int* i_cnt_out = (int*)alloc((size_t)RR * NN * 4);
    int* i_cnt_in  = (int*)alloc((size_t)RR * NN * 4);
    int* i_off     = (int*)alloc((size_t)RR * (NN + 1) * 4);
    int* i_cnts    = (int*)alloc((size_t)ES * RR * NN * 4);   // 30 MB slice counts/bases
    int2* i_srcw   = (int2*)alloc((size_t)RR * EE * 8);
    int* i_bsum    = (int*)alloc((size_t)RR * SNB * 4);
    unsigned short* Bt_feat = (unsigned short*)alloc(256 * 320 * 2);
    unsigned short* Bt_l0   = (unsigned short*)alloc(256 * 1024 * 2);
    unsigned short* Bt_l1   = (unsigned short*)alloc(256 * 1024 * 2);
    unsigned short* Bt_c1   = (unsigned short*)alloc(256 * 256 * 2);
    unsigned short* Bt_c2   = (unsigned short*)alloc(256 * 256 * 2);  // padded to 256 rows
    float* bias_l0 = (float*)alloc(HH * 4);
    float* bias_l1 = (float*)alloc(HH * 4);

    const float invM = 1.0f / (float)NN;

    // --- CSR + degrees (LDS-chunked, edge-slice parallel) ---
    (void)hipMemsetAsync(i_cnt_out, 0, (size_t)RR * NN * 4, stream);
    (void)hipMemsetAsync(f_stats, 0, 4 * 2 * HH * 4, stream);
    hist_out<<<dim3(NCHUNK, RR, 4), 256, 0, stream>>>(esrc, i_cnt_out);
    hist_slice<<<dim3(NCHUNK, RR, ES), 256, 0, stream>>>(edst, i_cnts);
    sum_slices<<<cdiv_h(RR * NN, 256), 256, 0, stream>>>(i_cnts, i_cnt_in);
    rs_kernel<<<cdiv_h(RR * NN, 256), 256, 0, stream>>>(i_cnt_out, i_cnt_in, f_rs_out, f_rs_in, RR * NN);
    scan_a<<<dim3(SNB, RR), 256, 0, stream>>>(i_cnt_in, i_bsum);
    scan_b<<<1, 64, 0, stream>>>(i_bsum, i_off);
    scan_c<<<dim3(SNB, RR), 256, 0, stream>>>(i_cnt_in, i_bsum, i_off);
    prefix_slices<<<cdiv_h(RR * NN, 256), 256, 0, stream>>>(i_off, i_cnts);
    fill_sliced<<<dim3(NCHUNK, RR, ES), 256, 0, stream>>>(esrc, edst, f_rs_out, i_cnts, i_srcw);

    // --- weight prep (bf16, transposed) ---
    convert_x<<<cdiv_h(MPAD * 80, 256), 256, 0, stream>>>(x, xpad);
    wprep_feat<<<256, 320, 0, stream>>>(W_feat, Bt_feat);
    wprep_layer<<<1024, 256, 0, stream>>>(skip_W, gcn_W, Bt_l0);
    wprep_layer<<<1024, 256, 0, stream>>>(skip_W + (size_t)HH * HH, gcn_W + (size_t)RR * HH * HH, Bt_l1);
    bias_layer<<<1, 256, 0, stream>>>(skip_b, gcn_b, bias_l0);
    bias_layer<<<1, 256, 0, stream>>>(skip_b + HH, gcn_b + (size_t)RR * HH, bias_l1);
    wprep_c1<<<256, 256, 0, stream>>>(W_c1, Bt_c1);
    wprep_c2<<<256, 256, 0, stream>>>(W_c2, Bt_c2);

    dim3 grid_G(1, MPAD / 64);    // BM=64: 1564 row tiles, BN=256 single column
    dim3 grid_A(cdiv_h(NN, 4), RR);
    const int nblk_a = cdiv_h(NN * 32, 256);
    float* st0 = f_stats;
    float* st1 = f_stats + 2 * HH;
    float* st2 = f_stats + 4 * HH;
    float* st3 = f_stats + 6 * HH;

    // --- feat_reduce: h = relu(BN(x @ W_feat + b_feat)) -> hcat[:,0:256] bf16 ---
    mfma_gemm<<<grid_G, 256, 0, stream>>>(xpad, 320, Bt_feat, b_feat, c_acc, HH, HH, 320, 1, st0);
    bn_coef<<<1, 256, 0, stream>>>(st0, g_feat, beta_feat, f_coef, invM);
    bn_apply_v<<<nblk_a, 256, 0, stream>>>(c_acc, f_coef, hcat, 1);

    // --- GCN layers: one K=1024 GEMM per layer ---
    for (int l = 0; l < LL; l++) {
        agg_bf16<<<grid_A, 256, 0, stream>>>(hcat, i_off, i_srcw, f_rs_in);
        float* st = l ? st2 : st1;
        mfma_gemm<<<grid_G, 256, 0, stream>>>(hcat, 1024, l ? Bt_l1 : Bt_l0,
                                              l ? bias_l1 : bias_l0, c_acc, HH, HH, 1024, 1, st);
        bn_coef<<<1, 256, 0, stream>>>(st, bn_g + (size_t)l * HH, bn_b + (size_t)l * HH, f_coef, invM);
        bn_apply_v<<<nblk_a, 256, 0, stream>>>(c_acc, f_coef, hcat, 2);
    }

    // --- head ---
    mfma_gemm<<<grid_G, 256, 0, stream>>>(hcat, 1024, Bt_c1, b_c1, c_acc, HH, HH, 256, 1, st3);
    bn_coef<<<1, 256, 0, stream>>>(st3, g_c, beta_c, f_coef, invM);
    bn_apply_v<<<nblk_a, 256, 0, stream>>>(c_acc, f_coef, hcat + 256, 1);
    mfma_gemm<<<grid_G, 256, 0, stream>>>(hcat + 256, 1024, Bt_c2, b_c2, out, CC, CC, 256, 0, nullptr);
}